// Round 7
// baseline (605.180 us; speedup 1.0000x reference)
//
#include <hip/hip_runtime.h>

#define N_NODES 65536
#define G_GRID  32768
#define E_EDGES 600000
#define HD      128

typedef __attribute__((ext_vector_type(8))) short bf8;
typedef __attribute__((ext_vector_type(4))) float f32x4;

__device__ __forceinline__ short f2bf(float f){
  union { float f; unsigned u; } v; v.f = f;
  unsigned r = v.u + 0x7FFFu + ((v.u >> 16) & 1u);
  return (short)(r >> 16);
}

__device__ __forceinline__ bf8 load_pack8(const float* p, float scale){
  float4 u0 = *(const float4*)p;
  float4 u1 = *(const float4*)(p + 4);
  bf8 r;
  r[0]=f2bf(u0.x*scale); r[1]=f2bf(u0.y*scale); r[2]=f2bf(u0.z*scale); r[3]=f2bf(u0.w*scale);
  r[4]=f2bf(u1.x*scale); r[5]=f2bf(u1.y*scale); r[6]=f2bf(u1.z*scale); r[7]=f2bf(u1.w*scale);
  return r;
}

// ---------- weight prep: transpose + bf16 ----------
__global__ void prep_w_k(const float* __restrict__ nmw1, const float* __restrict__ nmw2,
                         const float* __restrict__ emw2, const float* __restrict__ mmw1,
                         const float* __restrict__ mmw2, const float* __restrict__ umw1,
                         const float* __restrict__ umw2, short* __restrict__ dst)
{
  int i = blockIdx.x*256 + threadIdx.x;  // < 131072
  const float* src; int local; bool k256 = false;
  if      (i < 16384){ src = nmw1; local = i; }
  else if (i < 32768){ src = nmw2; local = i - 16384; }
  else if (i < 49152){ src = emw2; local = i - 32768; }
  else if (i < 81920){ src = mmw1; local = i - 49152; k256 = true; }
  else if (i < 98304){ src = mmw2; local = i - 81920; }
  else if (i < 114688){ src = umw1; local = i - 98304; }
  else               { src = umw2; local = i - 114688; }
  int n, k;
  if (k256){ n = local >> 8; k = local & 255; }
  else     { n = local >> 7; k = local & 127; }
  dst[i] = f2bf(src[k*HD + n]);
}

// ---------- fold prep (coalesced: lanes index n) ----------
__global__ void prep_combo_k(const float* __restrict__ emw1, const float* __restrict__ eb1,
                             const float* __restrict__ emw2, const float* __restrict__ eb2,
                             const float* __restrict__ mmw1, const float* __restrict__ mb1,
                             short* __restrict__ wcombot, float* __restrict__ bcombo,
                             float* __restrict__ ew1c)
{
  int gid = blockIdx.x*256 + threadIdx.x;
  if (gid < 16384){
    int k = gid >> 7, n = gid & 127;   // wave-uniform k, coalesced n
    float a0 = 0.f, a1 = 0.f;
    #pragma unroll 4
    for (int j=0;j<HD;j+=2){
      a0 += emw2[k*HD + j]     * mmw1[(HD + j)*HD + n];
      a1 += emw2[k*HD + j + 1] * mmw1[(HD + j + 1)*HD + n];
    }
    wcombot[n*HD + k] = f2bf(a0 + a1);
  } else if (gid < 16512){
    int n = gid - 16384;
    float acc = mb1[n];
    for (int j=0;j<HD;j++) acc += eb2[j] * mmw1[(HD + j)*HD + n];
    bcombo[n] = acc;
  } else if (gid < 16640){
    int n = gid - 16512;
    #pragma unroll
    for (int k=0;k<6;k++) ew1c[n*8 + k] = emw1[k*HD + n];
    ew1c[n*8 + 6] = eb1[n];
    ew1c[n*8 + 7] = 0.f;
  }
}

// ---------- node MLP (MFMA, wave-local hid slab -> no barrier) ----------
__global__ void node_mlp_k(const float* __restrict__ X,
                           const short* __restrict__ w1t, const float* __restrict__ b1,
                           const short* __restrict__ w2t, const float* __restrict__ b2,
                           short* __restrict__ nf)
{
  __shared__ short hid[64][136];
  const int t = threadIdx.x;
  const int wave = t >> 6, lane = t & 63, l15 = lane & 15, q = lane >> 4;
  const int rw = blockIdx.x*64 + wave*16;

  bf8 a[4];
  const float* xr = X + (size_t)(rw + l15)*HD;
  #pragma unroll
  for (int kt=0; kt<4; kt++) a[kt] = load_pack8(xr + kt*32 + q*8, 1.0f);

  #pragma unroll
  for (int ct=0; ct<8; ct++){
    f32x4 acc = {0.f,0.f,0.f,0.f};
    #pragma unroll
    for (int kt=0; kt<4; kt++){
      bf8 b = *(const bf8*)(w1t + (ct*16 + l15)*HD + kt*32 + q*8);
      acc = __builtin_amdgcn_mfma_f32_16x16x32_bf16(a[kt], b, acc, 0, 0, 0);
    }
    float bias = b1[ct*16 + l15];
    #pragma unroll
    for (int r=0;r<4;r++){
      float v = acc[r] + bias;
      v = v / (1.f + __expf(-v));
      hid[wave*16 + q*4 + r][ct*16 + l15] = f2bf(v);
    }
  }
  // hid slab is wave-local: no __syncthreads needed
  bf8 a2[4];
  #pragma unroll
  for (int kt=0;kt<4;kt++) a2[kt] = *(const bf8*)&hid[wave*16 + l15][kt*32 + q*8];
  #pragma unroll
  for (int ct=0; ct<8; ct++){
    f32x4 acc = {0.f,0.f,0.f,0.f};
    #pragma unroll
    for (int kt=0;kt<4;kt++){
      bf8 b = *(const bf8*)(w2t + (ct*16 + l15)*HD + kt*32 + q*8);
      acc = __builtin_amdgcn_mfma_f32_16x16x32_bf16(a2[kt], b, acc, 0, 0, 0);
    }
    float bias = b2[ct*16 + l15];
    #pragma unroll
    for (int r=0;r<4;r++)
      nf[(size_t)(rw + q*4 + r)*HD + ct*16 + l15] = f2bf(acc[r] + bias);
  }
}

// ---------- CSR build ----------
__global__ void count_k(const int* __restrict__ eidx, int* __restrict__ counts){
  int e = blockIdx.x*256 + threadIdx.x;
  if (e < E_EDGES) atomicAdd(&counts[eidx[E_EDGES + e]], 1);
}

__global__ void scan_k(const int* __restrict__ counts, int* __restrict__ offs){
  __shared__ int part[1024];
  const int t = threadIdx.x;
  const int base = t*32;
  int loc[32];
  int s = 0;
  #pragma unroll
  for (int i=0;i<32;i++){ loc[i] = s; s += counts[base+i]; }
  part[t] = s;
  __syncthreads();
  for (int off=1; off<1024; off<<=1){
    int v = (t>=off) ? part[t-off] : 0;
    __syncthreads();
    part[t] += v;
    __syncthreads();
  }
  int pre = (t==0) ? 0 : part[t-1];
  #pragma unroll
  for (int i=0;i<32;i++) offs[base+i] = pre + loc[i];
  if (t==1023) offs[G_GRID] = pre + s;
}

__global__ void scatter_k(const int* __restrict__ eidx, const int* __restrict__ offs,
                          int* __restrict__ counts,
                          int* __restrict__ srcs_s, int* __restrict__ tgts_s){
  int e = blockIdx.x*256 + threadIdx.x;
  if (e < E_EDGES){
    int g = eidx[E_EDGES + e];
    int slot = offs[g] + atomicSub(&counts[g], 1) - 1;
    srcs_s[slot] = eidx[e];
    tgts_s[slot] = g;
  }
}

// ---------- fused edge+message, BARRIER-FREE (one startup sync) ----------
// Wave w owns contiguous sorted edges [e0+w*32, e0+w*32+32) as two M=16 tiles.
// h computed in-register in A-fragment layout; per-wave LDS arena for the
// msg-hidden layout swap and the fp32 msg tile; wave-local segmented reduce.
__global__ void __launch_bounds__(256, 4)
edge_msg3_k(const int* __restrict__ srcs_s, const int* __restrict__ tgts_s,
            const float* __restrict__ npos, const float* __restrict__ gpos,
            const float* __restrict__ ew1c_g, const float* __restrict__ bcombo,
            const short* __restrict__ mw1t, const short* __restrict__ wcombot,
            const short* __restrict__ mw2t, const float* __restrict__ mb2,
            const short* __restrict__ nf, float* __restrict__ agg)
{
  __shared__ float ew1l[128][8];    // 4 KB  {w0..w5, b, pad}
  __shared__ int tgtl[128];         // 512 B
  union WArena {
    short hm[32][136];              // 8704 B msg-hidden (2 tiles)
    float msgf[16][132];            // 8448 B fp32 msg tile
  };
  __shared__ WArena ar[4];          // 34816 B  -> total 39424 B => 4 blocks/CU

  const int t = threadIdx.x;
  const int e0 = blockIdx.x*128;
  const int w = t >> 6, lane = t & 63, l15 = lane & 15, q = lane >> 4;
  const int base = e0 + w*32;       // wave's first edge (global sorted idx)

  // ---- all global gathers issued before the single barrier ----
  int i0 = base + l15;      if (i0 >= E_EDGES) i0 = E_EDGES - 1;
  int i1 = base + 16 + l15; if (i1 >= E_EDGES) i1 = E_EDGES - 1;
  int s0 = srcs_s[i0], s1 = srcs_s[i1];
  int g0 = tgts_s[i0], g1 = tgts_s[i1];

  bf8 an0[4], an1[4];
  {
    const short* n0p = nf + (size_t)s0*HD + q*8;
    const short* n1p = nf + (size_t)s1*HD + q*8;
    #pragma unroll
    for (int kt=0;kt<4;kt++){ an0[kt] = *(const bf8*)(n0p + kt*32); an1[kt] = *(const bf8*)(n1p + kt*32); }
  }
  float p0[6], p1[6];
  p0[0]=npos[s0*3+0]; p0[1]=npos[s0*3+1]; p0[2]=npos[s0*3+2];
  p0[3]=gpos[g0*3+0]; p0[4]=gpos[g0*3+1]; p0[5]=gpos[g0*3+2];
  p1[0]=npos[s1*3+0]; p1[1]=npos[s1*3+1]; p1[2]=npos[s1*3+2];
  p1[3]=gpos[g1*3+0]; p1[4]=gpos[g1*3+1]; p1[5]=gpos[g1*3+2];

  if (t < 128){
    int idx = e0 + t; if (idx >= E_EDGES) idx = E_EDGES - 1;
    tgtl[t] = tgts_s[idx];
    *(f32x4*)&ew1l[t][0] = *(const f32x4*)&ew1c_g[t*8];
    *(f32x4*)&ew1l[t][4] = *(const f32x4*)&ew1c_g[t*8 + 4];
  }
  __syncthreads();   // the ONLY block-wide barrier

  // ---- stage 1: h = silu(pos6@ew1+eb1), computed directly in A-frag layout ----
  bf8 ah0[4], ah1[4];
  #pragma unroll
  for (int kt=0;kt<4;kt++){
    #pragma unroll
    for (int j=0;j<8;j++){
      int n = kt*32 + q*8 + j;
      f32x4 wa = *(const f32x4*)&ew1l[n][0];
      f32x4 wb = *(const f32x4*)&ew1l[n][4];
      float v0 = wb[2] + p0[0]*wa[0] + p0[1]*wa[1] + p0[2]*wa[2]
                       + p0[3]*wa[3] + p0[4]*wb[0] + p0[5]*wb[1];
      v0 = v0 / (1.f + __expf(-v0));
      ah0[kt][j] = f2bf(v0);
      float v1 = wb[2] + p1[0]*wa[0] + p1[1]*wa[1] + p1[2]*wa[2]
                       + p1[3]*wa[3] + p1[4]*wb[0] + p1[5]*wb[1];
      v1 = v1 / (1.f + __expf(-v1));
      ah1[kt][j] = f2bf(v1);
    }
  }

  // ---- stage 2: msg_hidden = silu(an@mw1a + ah@W_combo + b_combo) -> wave arena ----
  #pragma unroll
  for (int ct=0; ct<8; ct++){
    bf8 bw1[4], bwc[4];
    #pragma unroll
    for (int kt=0;kt<4;kt++){
      bw1[kt] = *(const bf8*)(mw1t + (ct*16 + l15)*256 + kt*32 + q*8);
      bwc[kt] = *(const bf8*)(wcombot + (ct*16 + l15)*HD + kt*32 + q*8);
    }
    f32x4 acc0 = {0.f,0.f,0.f,0.f}, acc1 = {0.f,0.f,0.f,0.f};
    #pragma unroll
    for (int kt=0;kt<4;kt++){
      acc0 = __builtin_amdgcn_mfma_f32_16x16x32_bf16(an0[kt], bw1[kt], acc0, 0,0,0);
      acc1 = __builtin_amdgcn_mfma_f32_16x16x32_bf16(an1[kt], bw1[kt], acc1, 0,0,0);
    }
    #pragma unroll
    for (int kt=0;kt<4;kt++){
      acc0 = __builtin_amdgcn_mfma_f32_16x16x32_bf16(ah0[kt], bwc[kt], acc0, 0,0,0);
      acc1 = __builtin_amdgcn_mfma_f32_16x16x32_bf16(ah1[kt], bwc[kt], acc1, 0,0,0);
    }
    float bias = bcombo[ct*16 + l15];
    int col = ct*16 + l15;
    #pragma unroll
    for (int r=0;r<4;r++){
      float v0 = acc0[r] + bias;
      v0 = v0 / (1.f + __expf(-v0));
      ar[w].hm[q*4 + r][col] = f2bf(v0);
      float v1 = acc1[r] + bias;
      v1 = v1 / (1.f + __expf(-v1));
      ar[w].hm[16 + q*4 + r][col] = f2bf(v1);
    }
  }

  // read both am fragments BEFORE msgf aliases hm (wave-local ordering only)
  bf8 am0[4], am1[4];
  #pragma unroll
  for (int kt=0;kt<4;kt++){
    am0[kt] = *(const bf8*)&ar[w].hm[l15][kt*32 + q*8];
    am1[kt] = *(const bf8*)&ar[w].hm[16 + l15][kt*32 + q*8];
  }

  // ---- tile0: msg GEMM -> msgf -> wave-local segmented reduce ----
  #pragma unroll
  for (int ct=0; ct<8; ct++){
    f32x4 acc = {0.f,0.f,0.f,0.f};
    #pragma unroll
    for (int kt=0;kt<4;kt++){
      bf8 b = *(const bf8*)(mw2t + (ct*16 + l15)*HD + kt*32 + q*8);
      acc = __builtin_amdgcn_mfma_f32_16x16x32_bf16(am0[kt], b, acc, 0,0,0);
    }
    float bias = mb2[ct*16 + l15];
    int col = ct*16 + l15;
    #pragma unroll
    for (int r=0;r<4;r++) ar[w].msgf[q*4 + r][col] = acc[r] + bias;
  }
  {
    int lim = E_EDGES - base; if (lim > 16) lim = 16;
    if (lim > 0){
      int c2 = lane*2;
      int cur = tgtl[w*32];
      float sx = 0.f, sy = 0.f;
      for (int r=0; r<lim; r++){
        int tg = tgtl[w*32 + r];
        float2 v = *(const float2*)&ar[w].msgf[r][c2];
        if (tg != cur){
          atomicAdd(&agg[(size_t)cur*HD + c2], sx);
          atomicAdd(&agg[(size_t)cur*HD + c2 + 1], sy);
          cur = tg; sx = v.x; sy = v.y;
        } else { sx += v.x; sy += v.y; }
      }
      atomicAdd(&agg[(size_t)cur*HD + c2], sx);
      atomicAdd(&agg[(size_t)cur*HD + c2 + 1], sy);
    }
  }

  // ---- tile1 ----
  if (base + 16 < E_EDGES){
    #pragma unroll
    for (int ct=0; ct<8; ct++){
      f32x4 acc = {0.f,0.f,0.f,0.f};
      #pragma unroll
      for (int kt=0;kt<4;kt++){
        bf8 b = *(const bf8*)(mw2t + (ct*16 + l15)*HD + kt*32 + q*8);
        acc = __builtin_amdgcn_mfma_f32_16x16x32_bf16(am1[kt], b, acc, 0,0,0);
      }
      float bias = mb2[ct*16 + l15];
      int col = ct*16 + l15;
      #pragma unroll
      for (int r=0;r<4;r++) ar[w].msgf[q*4 + r][col] = acc[r] + bias;
    }
    int lim = E_EDGES - (base + 16); if (lim > 16) lim = 16;
    int c2 = lane*2;
    int cur = tgtl[w*32 + 16];
    float sx = 0.f, sy = 0.f;
    for (int r=0; r<lim; r++){
      int tg = tgtl[w*32 + 16 + r];
      float2 v = *(const float2*)&ar[w].msgf[r][c2];
      if (tg != cur){
        atomicAdd(&agg[(size_t)cur*HD + c2], sx);
        atomicAdd(&agg[(size_t)cur*HD + c2 + 1], sy);
        cur = tg; sx = v.x; sy = v.y;
      } else { sx += v.x; sy += v.y; }
    }
    atomicAdd(&agg[(size_t)cur*HD + c2], sx);
    atomicAdd(&agg[(size_t)cur*HD + c2 + 1], sy);
  }
}

// ---------- update MLP (MFMA bf16, wave-local, no barrier), in-place over agg(=d_out) ----------
__global__ void update_mlp2_k(const float* __restrict__ agg, const int* __restrict__ offs,
                              const short* __restrict__ w1t, const float* __restrict__ b1,
                              const short* __restrict__ w2t, const float* __restrict__ b2,
                              float* __restrict__ out)
{
  __shared__ short hid[64][136];
  const int t = threadIdx.x;
  const int wave = t >> 6, lane = t & 63, l15 = lane & 15, q = lane >> 4;
  const int rw = blockIdx.x*64 + wave*16;

  int row = rw + l15;
  float c = (float)(offs[row+1] - offs[row]);
  float rcp = 1.0f / fmaxf(c, 1.0f);
  bf8 a[4];
  const float* ar = agg + (size_t)row*HD;
  #pragma unroll
  for (int kt=0; kt<4; kt++) a[kt] = load_pack8(ar + kt*32 + q*8, rcp);

  #pragma unroll
  for (int ct=0; ct<8; ct++){
    f32x4 acc = {0.f,0.f,0.f,0.f};
    #pragma unroll
    for (int kt=0; kt<4; kt++){
      bf8 b = *(const bf8*)(w1t + (ct*16 + l15)*HD + kt*32 + q*8);
      acc = __builtin_amdgcn_mfma_f32_16x16x32_bf16(a[kt], b, acc, 0, 0, 0);
    }
    float bias = b1[ct*16 + l15];
    #pragma unroll
    for (int r=0;r<4;r++){
      float v = acc[r] + bias;
      v = v / (1.f + __expf(-v));
      hid[wave*16 + q*4 + r][ct*16 + l15] = f2bf(v);
    }
  }
  // wave-local hid slab: no barrier
  bf8 a2[4];
  #pragma unroll
  for (int kt=0;kt<4;kt++) a2[kt] = *(const bf8*)&hid[wave*16 + l15][kt*32 + q*8];
  #pragma unroll
  for (int ct=0; ct<8; ct++){
    f32x4 acc = {0.f,0.f,0.f,0.f};
    #pragma unroll
    for (int kt=0;kt<4;kt++){
      bf8 b = *(const bf8*)(w2t + (ct*16 + l15)*HD + kt*32 + q*8);
      acc = __builtin_amdgcn_mfma_f32_16x16x32_bf16(a2[kt], b, acc, 0, 0, 0);
    }
    float bias = b2[ct*16 + l15];
    #pragma unroll
    for (int r=0;r<4;r++)
      out[(size_t)(rw + q*4 + r)*HD + ct*16 + l15] = acc[r] + bias;
  }
}

extern "C" void kernel_launch(void* const* d_in, const int* in_sizes, int n_in,
                              void* d_out, int out_size, void* d_ws, size_t ws_size,
                              hipStream_t stream)
{
  const float* node_features = (const float*)d_in[0];
  const float* node_pos      = (const float*)d_in[1];
  const float* grid_pos      = (const float*)d_in[2];
  const int*   edge_index    = (const int*)d_in[3];
  const float* nm_w1 = (const float*)d_in[4];
  const float* nm_b1 = (const float*)d_in[5];
  const float* nm_w2 = (const float*)d_in[6];
  const float* nm_b2 = (const float*)d_in[7];
  const float* em_w1 = (const float*)d_in[8];
  const float* em_b1 = (const float*)d_in[9];
  const float* em_w2 = (const float*)d_in[10];
  const float* em_b2 = (const float*)d_in[11];
  const float* mm_w1 = (const float*)d_in[12];
  const float* mm_b1 = (const float*)d_in[13];
  const float* mm_w2 = (const float*)d_in[14];
  const float* mm_b2 = (const float*)d_in[15];
  const float* um_w1 = (const float*)d_in[16];
  const float* um_b1 = (const float*)d_in[17];
  const float* um_w2 = (const float*)d_in[18];
  const float* um_b2 = (const float*)d_in[19];
  float* out = (float*)d_out;

  char* ws = (char*)d_ws;
  short* nf     = (short*)ws;                        // 16 MB  bf16 [N,128]
  int*   counts = (int*)  (ws + 16777216ull);        // 128 KB
  int*   offs   = (int*)  (ws + 16908288ull);        // 128 KB + 64
  short* wts    = (short*)(ws + 17039424ull);        // 256 KB bf16 transposed
  short* wcombot= (short*)(ws + 17301568ull);        // 32 KB
  float* bcombo = (float*)(ws + 17334336ull);        // 512 B
  float* ew1c   = (float*)(ws + 17334848ull);        // 4 KB
  int*   srcs_s = (int*)  (ws + 17338944ull);        // 2.4 MB
  int*   tgts_s = (int*)  (ws + 19738944ull);        // 2.4 MB

  short* nmw1t = wts;
  short* nmw2t = wts + 16384;
  short* mmw1t = wts + 49152;   // [n][256]
  short* mmw2t = wts + 81920;
  short* umw1t = wts + 98304;
  short* umw2t = wts + 114688;

  float* agg = out;  // accumulate mean-numerator directly in d_out

  (void)hipMemsetAsync(counts, 0, 131072, stream);
  (void)hipMemsetAsync(out, 0, (size_t)G_GRID*HD*4, stream);

  prep_w_k<<<512, 256, 0, stream>>>(nm_w1, nm_w2, em_w2, mm_w1, mm_w2, um_w1, um_w2, wts);
  prep_combo_k<<<65, 256, 0, stream>>>(em_w1, em_b1, em_w2, em_b2, mm_w1, mm_b1,
                                       wcombot, bcombo, ew1c);
  node_mlp_k<<<N_NODES/64, 256, 0, stream>>>(node_features, nmw1t, nm_b1, nmw2t, nm_b2, nf);
  count_k<<<(E_EDGES+255)/256, 256, 0, stream>>>(edge_index, counts);
  scan_k<<<1, 1024, 0, stream>>>(counts, offs);
  scatter_k<<<(E_EDGES+255)/256, 256, 0, stream>>>(edge_index, offs, counts, srcs_s, tgts_s);
  edge_msg3_k<<<(E_EDGES + 127)/128, 256, 0, stream>>>(srcs_s, tgts_s, node_pos, grid_pos,
      ew1c, bcombo, mmw1t, wcombot, mmw2t, mm_b2, nf, agg);
  update_mlp2_k<<<G_GRID/64, 256, 0, stream>>>(agg, offs, umw1t, um_b1, umw2t, um_b2, out);
}

// Round 8
// 547.954 us; speedup vs baseline: 1.1044x; 1.1044x over previous
//
#include <hip/hip_runtime.h>

#define N_NODES 65536
#define G_GRID  32768
#define E_EDGES 600000
#define HD      128

typedef __attribute__((ext_vector_type(8))) short bf8;
typedef __attribute__((ext_vector_type(4))) float f32x4;

__device__ __forceinline__ short f2bf(float f){
  union { float f; unsigned u; } v; v.f = f;
  unsigned r = v.u + 0x7FFFu + ((v.u >> 16) & 1u);
  return (short)(r >> 16);
}

__device__ __forceinline__ bf8 load_pack8(const float* p, float scale){
  float4 u0 = *(const float4*)p;
  float4 u1 = *(const float4*)(p + 4);
  bf8 r;
  r[0]=f2bf(u0.x*scale); r[1]=f2bf(u0.y*scale); r[2]=f2bf(u0.z*scale); r[3]=f2bf(u0.w*scale);
  r[4]=f2bf(u1.x*scale); r[5]=f2bf(u1.y*scale); r[6]=f2bf(u1.z*scale); r[7]=f2bf(u1.w*scale);
  return r;
}

// ---------- weight prep: transpose + bf16 ----------
__global__ void prep_w_k(const float* __restrict__ nmw1, const float* __restrict__ nmw2,
                         const float* __restrict__ emw2, const float* __restrict__ mmw1,
                         const float* __restrict__ mmw2, const float* __restrict__ umw1,
                         const float* __restrict__ umw2, short* __restrict__ dst)
{
  int i = blockIdx.x*256 + threadIdx.x;  // < 131072
  const float* src; int local; bool k256 = false;
  if      (i < 16384){ src = nmw1; local = i; }
  else if (i < 32768){ src = nmw2; local = i - 16384; }
  else if (i < 49152){ src = emw2; local = i - 32768; }
  else if (i < 81920){ src = mmw1; local = i - 49152; k256 = true; }
  else if (i < 98304){ src = mmw2; local = i - 81920; }
  else if (i < 114688){ src = umw1; local = i - 98304; }
  else               { src = umw2; local = i - 114688; }
  int n, k;
  if (k256){ n = local >> 8; k = local & 255; }
  else     { n = local >> 7; k = local & 127; }
  dst[i] = f2bf(src[k*HD + n]);
}

// ---------- fold prep (coalesced: lanes index n) ----------
__global__ void prep_combo_k(const float* __restrict__ emw1, const float* __restrict__ eb1,
                             const float* __restrict__ emw2, const float* __restrict__ eb2,
                             const float* __restrict__ mmw1, const float* __restrict__ mb1,
                             short* __restrict__ wcombot, float* __restrict__ bcombo,
                             float* __restrict__ ew1c)
{
  int gid = blockIdx.x*256 + threadIdx.x;
  if (gid < 16384){
    int k = gid >> 7, n = gid & 127;   // wave-uniform k, coalesced n
    float a0 = 0.f, a1 = 0.f;
    #pragma unroll 4
    for (int j=0;j<HD;j+=2){
      a0 += emw2[k*HD + j]     * mmw1[(HD + j)*HD + n];
      a1 += emw2[k*HD + j + 1] * mmw1[(HD + j + 1)*HD + n];
    }
    wcombot[n*HD + k] = f2bf(a0 + a1);
  } else if (gid < 16512){
    int n = gid - 16384;
    float acc = mb1[n];
    for (int j=0;j<HD;j++) acc += eb2[j] * mmw1[(HD + j)*HD + n];
    bcombo[n] = acc;
  } else if (gid < 16640){
    int n = gid - 16512;
    #pragma unroll
    for (int k=0;k<6;k++) ew1c[n*8 + k] = emw1[k*HD + n];
    ew1c[n*8 + 6] = eb1[n];
    ew1c[n*8 + 7] = 0.f;
  }
}

// ---------- node MLP (MFMA, wave-local hid slab -> no barrier) ----------
__global__ void node_mlp_k(const float* __restrict__ X,
                           const short* __restrict__ w1t, const float* __restrict__ b1,
                           const short* __restrict__ w2t, const float* __restrict__ b2,
                           short* __restrict__ nf)
{
  __shared__ short hid[64][136];
  const int t = threadIdx.x;
  const int wave = t >> 6, lane = t & 63, l15 = lane & 15, q = lane >> 4;
  const int rw = blockIdx.x*64 + wave*16;

  bf8 a[4];
  const float* xr = X + (size_t)(rw + l15)*HD;
  #pragma unroll
  for (int kt=0; kt<4; kt++) a[kt] = load_pack8(xr + kt*32 + q*8, 1.0f);

  #pragma unroll
  for (int ct=0; ct<8; ct++){
    f32x4 acc = {0.f,0.f,0.f,0.f};
    #pragma unroll
    for (int kt=0; kt<4; kt++){
      bf8 b = *(const bf8*)(w1t + (ct*16 + l15)*HD + kt*32 + q*8);
      acc = __builtin_amdgcn_mfma_f32_16x16x32_bf16(a[kt], b, acc, 0, 0, 0);
    }
    float bias = b1[ct*16 + l15];
    #pragma unroll
    for (int r=0;r<4;r++){
      float v = acc[r] + bias;
      v = v / (1.f + __expf(-v));
      hid[wave*16 + q*4 + r][ct*16 + l15] = f2bf(v);
    }
  }
  bf8 a2[4];
  #pragma unroll
  for (int kt=0;kt<4;kt++) a2[kt] = *(const bf8*)&hid[wave*16 + l15][kt*32 + q*8];
  #pragma unroll
  for (int ct=0; ct<8; ct++){
    f32x4 acc = {0.f,0.f,0.f,0.f};
    #pragma unroll
    for (int kt=0;kt<4;kt++){
      bf8 b = *(const bf8*)(w2t + (ct*16 + l15)*HD + kt*32 + q*8);
      acc = __builtin_amdgcn_mfma_f32_16x16x32_bf16(a2[kt], b, acc, 0, 0, 0);
    }
    float bias = b2[ct*16 + l15];
    #pragma unroll
    for (int r=0;r<4;r++)
      nf[(size_t)(rw + q*4 + r)*HD + ct*16 + l15] = f2bf(acc[r] + bias);
  }
}

// ---------- CSR build ----------
__global__ void count_k(const int* __restrict__ eidx, int* __restrict__ counts){
  int e = blockIdx.x*256 + threadIdx.x;
  if (e < E_EDGES) atomicAdd(&counts[eidx[E_EDGES + e]], 1);
}

__global__ void scan_k(const int* __restrict__ counts, int* __restrict__ offs){
  __shared__ int part[1024];
  const int t = threadIdx.x;
  const int base = t*32;
  int loc[32];
  int s = 0;
  #pragma unroll
  for (int i=0;i<32;i++){ loc[i] = s; s += counts[base+i]; }
  part[t] = s;
  __syncthreads();
  for (int off=1; off<1024; off<<=1){
    int v = (t>=off) ? part[t-off] : 0;
    __syncthreads();
    part[t] += v;
    __syncthreads();
  }
  int pre = (t==0) ? 0 : part[t-1];
  #pragma unroll
  for (int i=0;i<32;i++) offs[base+i] = pre + loc[i];
  if (t==1023) offs[G_GRID] = pre + s;
}

__global__ void scatter_k(const int* __restrict__ eidx, const int* __restrict__ offs,
                          int* __restrict__ counts,
                          int* __restrict__ srcs_s, int* __restrict__ tgts_s){
  int e = blockIdx.x*256 + threadIdx.x;
  if (e < E_EDGES){
    int g = eidx[E_EDGES + e];
    int slot = offs[g] + atomicSub(&counts[g], 1) - 1;
    srcs_s[slot] = eidx[e];
    tgts_s[slot] = g;
  }
}

// ---------- fused edge+message: ONE barrier, all intermediates LDS-backed ----------
// Wave w owns hm rows [w*32, w*32+32) = sorted edges [e0+w*32, +32) (two 16-row tiles).
// Stage1 h written wave-locally into hm; msg-hidden overwrites hm (ah in regs);
// per-wave fp32 msgf arena aliases own hm rows; reduce carries across tiles.
__global__ void __launch_bounds__(256, 3)
edge_msg4_k(const int* __restrict__ srcs_s, const int* __restrict__ tgts_s,
            const float* __restrict__ npos, const float* __restrict__ gpos,
            const float* __restrict__ ew1c_g, const float* __restrict__ bcombo,
            const short* __restrict__ mw1t, const short* __restrict__ wcombot,
            const short* __restrict__ mw2t, const float* __restrict__ mb2,
            const short* __restrict__ nf, float* __restrict__ agg)
{
  __shared__ float ew1l[128][8];    // 4 KB {w0..w5, b, pad}
  __shared__ float attr[128][8];    // 4 KB (6 used)
  __shared__ int tgtl[128];         // 512 B
  __shared__ short hm[128][136];    // 34816 B   -> total 43.5 KB => 3 blocks/CU

  const int t = threadIdx.x;
  const int e0 = blockIdx.x*128;
  const int w = t >> 6, lane = t & 63, l15 = lane & 15, q = lane >> 4;
  const int base = e0 + w*32;

  // ---- early global gathers (before the single barrier) ----
  int i0 = base + l15;      if (i0 >= E_EDGES) i0 = E_EDGES - 1;
  int i1 = base + 16 + l15; if (i1 >= E_EDGES) i1 = E_EDGES - 1;
  int s0 = srcs_s[i0], s1 = srcs_s[i1];
  bf8 an0[4], an1[4];
  {
    const short* n0p = nf + (size_t)s0*HD + q*8;
    const short* n1p = nf + (size_t)s1*HD + q*8;
    #pragma unroll
    for (int kt=0;kt<4;kt++){ an0[kt] = *(const bf8*)(n0p + kt*32); an1[kt] = *(const bf8*)(n1p + kt*32); }
  }

  if (t < 128){
    int idx = e0 + t; if (idx >= E_EDGES) idx = E_EDGES - 1;
    int s = srcs_s[idx], g = tgts_s[idx];
    tgtl[t] = g;
    attr[t][0] = npos[s*3+0]; attr[t][1] = npos[s*3+1]; attr[t][2] = npos[s*3+2];
    attr[t][3] = gpos[g*3+0]; attr[t][4] = gpos[g*3+1]; attr[t][5] = gpos[g*3+2];
    *(f32x4*)&ew1l[t][0] = *(const f32x4*)&ew1c_g[t*8];
    *(f32x4*)&ew1l[t][4] = *(const f32x4*)&ew1c_g[t*8 + 4];
  }
  __syncthreads();   // the ONLY block-wide barrier

  // ---- stage 1: h = silu(pos6@ew1+eb1) -> hm, wave-local rows ----
  {
    int r0 = w*32 + l15, r1 = r0 + 16;   // hm row == block-local edge index
    float a0=attr[r0][0], a1=attr[r0][1], a2=attr[r0][2],
          a3=attr[r0][3], a4=attr[r0][4], a5=attr[r0][5];
    float b0=attr[r1][0], b1=attr[r1][1], b2=attr[r1][2],
          b3=attr[r1][3], b4=attr[r1][4], b5=attr[r1][5];
    #pragma unroll
    for (int pg=0; pg<4; pg++){
      bf8 pk0, pk1;
      #pragma unroll
      for (int j=0;j<8;j++){
        int n = q*32 + pg*8 + j;
        f32x4 wa = *(const f32x4*)&ew1l[n][0];
        f32x4 wb = *(const f32x4*)&ew1l[n][4];
        float v0 = wb[2] + a0*wa[0] + a1*wa[1] + a2*wa[2] + a3*wa[3] + a4*wb[0] + a5*wb[1];
        v0 = v0 / (1.f + __expf(-v0));
        pk0[j] = f2bf(v0);
        float v1 = wb[2] + b0*wa[0] + b1*wa[1] + b2*wa[2] + b3*wa[3] + b4*wb[0] + b5*wb[1];
        v1 = v1 / (1.f + __expf(-v1));
        pk1[j] = f2bf(v1);
      }
      *(bf8*)&hm[r0][q*32 + pg*8] = pk0;
      *(bf8*)&hm[r1][q*32 + pg*8] = pk1;
    }
  }

  // ---- stage 2: msg_hidden = silu(an@mw1a + ah@W_combo + b_combo) -> hm (overwrite) ----
  bf8 ah0[4], ah1[4];
  #pragma unroll
  for (int kt=0;kt<4;kt++){
    ah0[kt] = *(const bf8*)&hm[w*32 + l15][kt*32 + q*8];
    ah1[kt] = *(const bf8*)&hm[w*32 + 16 + l15][kt*32 + q*8];
  }
  #pragma unroll
  for (int ct=0; ct<8; ct++){
    bf8 bw1[4], bwc[4];
    #pragma unroll
    for (int kt=0;kt<4;kt++){
      bw1[kt] = *(const bf8*)(mw1t + (ct*16 + l15)*256 + kt*32 + q*8);
      bwc[kt] = *(const bf8*)(wcombot + (ct*16 + l15)*HD + kt*32 + q*8);
    }
    f32x4 acc0 = {0.f,0.f,0.f,0.f}, acc1 = {0.f,0.f,0.f,0.f};
    #pragma unroll
    for (int kt=0;kt<4;kt++){
      acc0 = __builtin_amdgcn_mfma_f32_16x16x32_bf16(an0[kt], bw1[kt], acc0, 0,0,0);
      acc1 = __builtin_amdgcn_mfma_f32_16x16x32_bf16(an1[kt], bw1[kt], acc1, 0,0,0);
    }
    #pragma unroll
    for (int kt=0;kt<4;kt++){
      acc0 = __builtin_amdgcn_mfma_f32_16x16x32_bf16(ah0[kt], bwc[kt], acc0, 0,0,0);
      acc1 = __builtin_amdgcn_mfma_f32_16x16x32_bf16(ah1[kt], bwc[kt], acc1, 0,0,0);
    }
    float bias = bcombo[ct*16 + l15];
    int col = ct*16 + l15;
    #pragma unroll
    for (int r=0;r<4;r++){
      float v0 = acc0[r] + bias;
      v0 = v0 / (1.f + __expf(-v0));
      hm[w*32 + q*4 + r][col] = f2bf(v0);
      float v1 = acc1[r] + bias;
      v1 = v1 / (1.f + __expf(-v1));
      hm[w*32 + 16 + q*4 + r][col] = f2bf(v1);
    }
  }

  // read BOTH am fragments before msgf aliases the wave's hm rows
  bf8 am0[4], am1[4];
  #pragma unroll
  for (int kt=0;kt<4;kt++){
    am0[kt] = *(const bf8*)&hm[w*32 + l15][kt*32 + q*8];
    am1[kt] = *(const bf8*)&hm[w*32 + 16 + l15][kt*32 + q*8];
  }

  float* msgf_w = (float*)&hm[w*32][0];   // per-wave fp32 arena [16][132]
  int lim0 = E_EDGES - base;      if (lim0 > 16) lim0 = 16;
  int lim1 = E_EDGES - base - 16; if (lim1 > 16) lim1 = 16;
  int c2 = lane*2;
  int cur = -1; float sx = 0.f, sy = 0.f;

  // ---- tile0: msg GEMM -> msgf -> wave-local segmented reduce (carry cur/sum) ----
  #pragma unroll
  for (int ct=0; ct<8; ct++){
    f32x4 acc = {0.f,0.f,0.f,0.f};
    #pragma unroll
    for (int kt=0;kt<4;kt++){
      bf8 b = *(const bf8*)(mw2t + (ct*16 + l15)*HD + kt*32 + q*8);
      acc = __builtin_amdgcn_mfma_f32_16x16x32_bf16(am0[kt], b, acc, 0,0,0);
    }
    float bias = mb2[ct*16 + l15];
    int col = ct*16 + l15;
    #pragma unroll
    for (int r=0;r<4;r++) msgf_w[(q*4 + r)*132 + col] = acc[r] + bias;
  }
  if (lim0 > 0){
    cur = tgtl[w*32];
    for (int r=0; r<lim0; r++){
      int tg = tgtl[w*32 + r];
      float2 v = *(const float2*)&msgf_w[r*132 + c2];
      if (tg != cur){
        atomicAdd(&agg[(size_t)cur*HD + c2], sx);
        atomicAdd(&agg[(size_t)cur*HD + c2 + 1], sy);
        cur = tg; sx = v.x; sy = v.y;
      } else { sx += v.x; sy += v.y; }
    }
  }

  // ---- tile1: GEMM overwrites arena (tile0 already consumed), continue reduce ----
  if (lim1 > 0){
    #pragma unroll
    for (int ct=0; ct<8; ct++){
      f32x4 acc = {0.f,0.f,0.f,0.f};
      #pragma unroll
      for (int kt=0;kt<4;kt++){
        bf8 b = *(const bf8*)(mw2t + (ct*16 + l15)*HD + kt*32 + q*8);
        acc = __builtin_amdgcn_mfma_f32_16x16x32_bf16(am1[kt], b, acc, 0,0,0);
      }
      float bias = mb2[ct*16 + l15];
      int col = ct*16 + l15;
      #pragma unroll
      for (int r=0;r<4;r++) msgf_w[(q*4 + r)*132 + col] = acc[r] + bias;
    }
    for (int r=0; r<lim1; r++){
      int tg = tgtl[w*32 + 16 + r];
      float2 v = *(const float2*)&msgf_w[r*132 + c2];
      if (tg != cur){
        atomicAdd(&agg[(size_t)cur*HD + c2], sx);
        atomicAdd(&agg[(size_t)cur*HD + c2 + 1], sy);
        cur = tg; sx = v.x; sy = v.y;
      } else { sx += v.x; sy += v.y; }
    }
  }
  if (cur >= 0){
    atomicAdd(&agg[(size_t)cur*HD + c2], sx);
    atomicAdd(&agg[(size_t)cur*HD + c2 + 1], sy);
  }
}

// ---------- update MLP (MFMA bf16, wave-local, no barrier), in-place over agg(=d_out) ----------
__global__ void update_mlp2_k(const float* __restrict__ agg, const int* __restrict__ offs,
                              const short* __restrict__ w1t, const float* __restrict__ b1,
                              const short* __restrict__ w2t, const float* __restrict__ b2,
                              float* __restrict__ out)
{
  __shared__ short hid[64][136];
  const int t = threadIdx.x;
  const int wave = t >> 6, lane = t & 63, l15 = lane & 15, q = lane >> 4;
  const int rw = blockIdx.x*64 + wave*16;

  int row = rw + l15;
  float c = (float)(offs[row+1] - offs[row]);
  float rcp = 1.0f / fmaxf(c, 1.0f);
  bf8 a[4];
  const float* ar = agg + (size_t)row*HD;
  #pragma unroll
  for (int kt=0; kt<4; kt++) a[kt] = load_pack8(ar + kt*32 + q*8, rcp);

  #pragma unroll
  for (int ct=0; ct<8; ct++){
    f32x4 acc = {0.f,0.f,0.f,0.f};
    #pragma unroll
    for (int kt=0; kt<4; kt++){
      bf8 b = *(const bf8*)(w1t + (ct*16 + l15)*HD + kt*32 + q*8);
      acc = __builtin_amdgcn_mfma_f32_16x16x32_bf16(a[kt], b, acc, 0, 0, 0);
    }
    float bias = b1[ct*16 + l15];
    #pragma unroll
    for (int r=0;r<4;r++){
      float v = acc[r] + bias;
      v = v / (1.f + __expf(-v));
      hid[wave*16 + q*4 + r][ct*16 + l15] = f2bf(v);
    }
  }
  bf8 a2[4];
  #pragma unroll
  for (int kt=0;kt<4;kt++) a2[kt] = *(const bf8*)&hid[wave*16 + l15][kt*32 + q*8];
  #pragma unroll
  for (int ct=0; ct<8; ct++){
    f32x4 acc = {0.f,0.f,0.f,0.f};
    #pragma unroll
    for (int kt=0;kt<4;kt++){
      bf8 b = *(const bf8*)(w2t + (ct*16 + l15)*HD + kt*32 + q*8);
      acc = __builtin_amdgcn_mfma_f32_16x16x32_bf16(a2[kt], b, acc, 0, 0, 0);
    }
    float bias = b2[ct*16 + l15];
    #pragma unroll
    for (int r=0;r<4;r++)
      out[(size_t)(rw + q*4 + r)*HD + ct*16 + l15] = acc[r] + bias;
  }
}

extern "C" void kernel_launch(void* const* d_in, const int* in_sizes, int n_in,
                              void* d_out, int out_size, void* d_ws, size_t ws_size,
                              hipStream_t stream)
{
  const float* node_features = (const float*)d_in[0];
  const float* node_pos      = (const float*)d_in[1];
  const float* grid_pos      = (const float*)d_in[2];
  const int*   edge_index    = (const int*)d_in[3];
  const float* nm_w1 = (const float*)d_in[4];
  const float* nm_b1 = (const float*)d_in[5];
  const float* nm_w2 = (const float*)d_in[6];
  const float* nm_b2 = (const float*)d_in[7];
  const float* em_w1 = (const float*)d_in[8];
  const float* em_b1 = (const float*)d_in[9];
  const float* em_w2 = (const float*)d_in[10];
  const float* em_b2 = (const float*)d_in[11];
  const float* mm_w1 = (const float*)d_in[12];
  const float* mm_b1 = (const float*)d_in[13];
  const float* mm_w2 = (const float*)d_in[14];
  const float* mm_b2 = (const float*)d_in[15];
  const float* um_w1 = (const float*)d_in[16];
  const float* um_b1 = (const float*)d_in[17];
  const float* um_w2 = (const float*)d_in[18];
  const float* um_b2 = (const float*)d_in[19];
  float* out = (float*)d_out;

  char* ws = (char*)d_ws;
  short* nf     = (short*)ws;                        // 16 MB  bf16 [N,128]
  int*   counts = (int*)  (ws + 16777216ull);        // 128 KB
  int*   offs   = (int*)  (ws + 16908288ull);        // 128 KB + 64
  short* wts    = (short*)(ws + 17039424ull);        // 256 KB bf16 transposed
  short* wcombot= (short*)(ws + 17301568ull);        // 32 KB
  float* bcombo = (float*)(ws + 17334336ull);        // 512 B
  float* ew1c   = (float*)(ws + 17334848ull);        // 4 KB
  int*   srcs_s = (int*)  (ws + 17338944ull);        // 2.4 MB
  int*   tgts_s = (int*)  (ws + 19738944ull);        // 2.4 MB

  short* nmw1t = wts;
  short* nmw2t = wts + 16384;
  short* mmw1t = wts + 49152;   // [n][256]
  short* mmw2t = wts + 81920;
  short* umw1t = wts + 98304;
  short* umw2t = wts + 114688;

  float* agg = out;  // accumulate mean-numerator directly in d_out

  (void)hipMemsetAsync(counts, 0, 131072, stream);
  (void)hipMemsetAsync(out, 0, (size_t)G_GRID*HD*4, stream);

  prep_w_k<<<512, 256, 0, stream>>>(nm_w1, nm_w2, em_w2, mm_w1, mm_w2, um_w1, um_w2, wts);
  prep_combo_k<<<65, 256, 0, stream>>>(em_w1, em_b1, em_w2, em_b2, mm_w1, mm_b1,
                                       wcombot, bcombo, ew1c);
  node_mlp_k<<<N_NODES/64, 256, 0, stream>>>(node_features, nmw1t, nm_b1, nmw2t, nm_b2, nf);
  count_k<<<(E_EDGES+255)/256, 256, 0, stream>>>(edge_index, counts);
  scan_k<<<1, 1024, 0, stream>>>(counts, offs);
  scatter_k<<<(E_EDGES+255)/256, 256, 0, stream>>>(edge_index, offs, counts, srcs_s, tgts_s);
  edge_msg4_k<<<(E_EDGES + 127)/128, 256, 0, stream>>>(srcs_s, tgts_s, node_pos, grid_pos,
      ew1c, bcombo, mmw1t, wcombot, mmw2t, mm_b2, nf, agg);
  update_mlp2_k<<<G_GRID/64, 256, 0, stream>>>(agg, offs, umw1t, um_b1, umw2t, um_b2, out);
}

// Round 9
// 538.736 us; speedup vs baseline: 1.1233x; 1.0171x over previous
//
#include <hip/hip_runtime.h>

#define N_NODES 65536
#define G_GRID  32768
#define E_EDGES 600000
#define HD      128

typedef __attribute__((ext_vector_type(8))) short bf8;
typedef __attribute__((ext_vector_type(4))) float f32x4;

__device__ __forceinline__ short f2bf(float f){
  union { float f; unsigned u; } v; v.f = f;
  unsigned r = v.u + 0x7FFFu + ((v.u >> 16) & 1u);
  return (short)(r >> 16);
}

__device__ __forceinline__ bf8 load_pack8(const float* p, float scale){
  float4 u0 = *(const float4*)p;
  float4 u1 = *(const float4*)(p + 4);
  bf8 r;
  r[0]=f2bf(u0.x*scale); r[1]=f2bf(u0.y*scale); r[2]=f2bf(u0.z*scale); r[3]=f2bf(u0.w*scale);
  r[4]=f2bf(u1.x*scale); r[5]=f2bf(u1.y*scale); r[6]=f2bf(u1.z*scale); r[7]=f2bf(u1.w*scale);
  return r;
}

// ---------- weight prep: transpose + bf16 ----------
__global__ void prep_w_k(const float* __restrict__ nmw1, const float* __restrict__ nmw2,
                         const float* __restrict__ emw2, const float* __restrict__ mmw1,
                         const float* __restrict__ mmw2, const float* __restrict__ umw1,
                         const float* __restrict__ umw2, short* __restrict__ dst)
{
  int i = blockIdx.x*256 + threadIdx.x;  // < 131072
  const float* src; int local; bool k256 = false;
  if      (i < 16384){ src = nmw1; local = i; }
  else if (i < 32768){ src = nmw2; local = i - 16384; }
  else if (i < 49152){ src = emw2; local = i - 32768; }
  else if (i < 81920){ src = mmw1; local = i - 49152; k256 = true; }
  else if (i < 98304){ src = mmw2; local = i - 81920; }
  else if (i < 114688){ src = umw1; local = i - 98304; }
  else               { src = umw2; local = i - 114688; }
  int n, k;
  if (k256){ n = local >> 8; k = local & 255; }
  else     { n = local >> 7; k = local & 127; }
  dst[i] = f2bf(src[k*HD + n]);
}

// ---------- fold prep (coalesced: lanes index n) ----------
__global__ void prep_combo_k(const float* __restrict__ emw1, const float* __restrict__ eb1,
                             const float* __restrict__ emw2, const float* __restrict__ eb2,
                             const float* __restrict__ mmw1, const float* __restrict__ mb1,
                             short* __restrict__ wcombot, float* __restrict__ bcombo,
                             float* __restrict__ ew1c)
{
  int gid = blockIdx.x*256 + threadIdx.x;
  if (gid < 16384){
    int k = gid >> 7, n = gid & 127;   // wave-uniform k, coalesced n
    float a0 = 0.f, a1 = 0.f;
    #pragma unroll 4
    for (int j=0;j<HD;j+=2){
      a0 += emw2[k*HD + j]     * mmw1[(HD + j)*HD + n];
      a1 += emw2[k*HD + j + 1] * mmw1[(HD + j + 1)*HD + n];
    }
    wcombot[n*HD + k] = f2bf(a0 + a1);
  } else if (gid < 16512){
    int n = gid - 16384;
    float acc = mb1[n];
    for (int j=0;j<HD;j++) acc += eb2[j] * mmw1[(HD + j)*HD + n];
    bcombo[n] = acc;
  } else if (gid < 16640){
    int n = gid - 16512;
    #pragma unroll
    for (int k=0;k<6;k++) ew1c[n*8 + k] = emw1[k*HD + n];
    ew1c[n*8 + 6] = eb1[n];
    ew1c[n*8 + 7] = 0.f;
  }
}

// ---------- node MLP (MFMA, wave-local hid slab -> no barrier) ----------
__global__ void node_mlp_k(const float* __restrict__ X,
                           const short* __restrict__ w1t, const float* __restrict__ b1,
                           const short* __restrict__ w2t, const float* __restrict__ b2,
                           short* __restrict__ nf)
{
  __shared__ short hid[64][136];
  const int t = threadIdx.x;
  const int wave = t >> 6, lane = t & 63, l15 = lane & 15, q = lane >> 4;
  const int rw = blockIdx.x*64 + wave*16;

  bf8 a[4];
  const float* xr = X + (size_t)(rw + l15)*HD;
  #pragma unroll
  for (int kt=0; kt<4; kt++) a[kt] = load_pack8(xr + kt*32 + q*8, 1.0f);

  #pragma unroll
  for (int ct=0; ct<8; ct++){
    f32x4 acc = {0.f,0.f,0.f,0.f};
    #pragma unroll
    for (int kt=0; kt<4; kt++){
      bf8 b = *(const bf8*)(w1t + (ct*16 + l15)*HD + kt*32 + q*8);
      acc = __builtin_amdgcn_mfma_f32_16x16x32_bf16(a[kt], b, acc, 0, 0, 0);
    }
    float bias = b1[ct*16 + l15];
    #pragma unroll
    for (int r=0;r<4;r++){
      float v = acc[r] + bias;
      v = v / (1.f + __expf(-v));
      hid[wave*16 + q*4 + r][ct*16 + l15] = f2bf(v);
    }
  }
  bf8 a2[4];
  #pragma unroll
  for (int kt=0;kt<4;kt++) a2[kt] = *(const bf8*)&hid[wave*16 + l15][kt*32 + q*8];
  #pragma unroll
  for (int ct=0; ct<8; ct++){
    f32x4 acc = {0.f,0.f,0.f,0.f};
    #pragma unroll
    for (int kt=0;kt<4;kt++){
      bf8 b = *(const bf8*)(w2t + (ct*16 + l15)*HD + kt*32 + q*8);
      acc = __builtin_amdgcn_mfma_f32_16x16x32_bf16(a2[kt], b, acc, 0, 0, 0);
    }
    float bias = b2[ct*16 + l15];
    #pragma unroll
    for (int r=0;r<4;r++)
      nf[(size_t)(rw + q*4 + r)*HD + ct*16 + l15] = f2bf(acc[r] + bias);
  }
}

// ---------- CSR build ----------
__global__ void count_k(const int* __restrict__ eidx, int* __restrict__ counts){
  int e = blockIdx.x*256 + threadIdx.x;
  if (e < E_EDGES) atomicAdd(&counts[eidx[E_EDGES + e]], 1);
}

__global__ void scan_k(const int* __restrict__ counts, int* __restrict__ offs){
  __shared__ int part[1024];
  const int t = threadIdx.x;
  const int base = t*32;
  int loc[32];
  int s = 0;
  #pragma unroll
  for (int i=0;i<32;i++){ loc[i] = s; s += counts[base+i]; }
  part[t] = s;
  __syncthreads();
  for (int off=1; off<1024; off<<=1){
    int v = (t>=off) ? part[t-off] : 0;
    __syncthreads();
    part[t] += v;
    __syncthreads();
  }
  int pre = (t==0) ? 0 : part[t-1];
  #pragma unroll
  for (int i=0;i<32;i++) offs[base+i] = pre + loc[i];
  if (t==1023) offs[G_GRID] = pre + s;
}

__global__ void scatter_k(const int* __restrict__ eidx, const int* __restrict__ offs,
                          int* __restrict__ counts,
                          int* __restrict__ srcs_s, int* __restrict__ tgts_s){
  int e = blockIdx.x*256 + threadIdx.x;
  if (e < E_EDGES){
    int g = eidx[E_EDGES + e];
    int slot = offs[g] + atomicSub(&counts[g], 1) - 1;
    srcs_s[slot] = eidx[e];
    tgts_s[slot] = g;
  }
}

// ---------- fused edge+message: ONE barrier, LDS-backed, 38.5 KB -> 4 blocks/CU ----------
__global__ void __launch_bounds__(256, 3)
edge_msg5_k(const int* __restrict__ srcs_s, const int* __restrict__ tgts_s,
            const float* __restrict__ npos, const float* __restrict__ gpos,
            const float* __restrict__ ew1c_g, const float* __restrict__ bcombo,
            const short* __restrict__ mw1t, const short* __restrict__ wcombot,
            const short* __restrict__ mw2t, const float* __restrict__ mb2,
            const short* __restrict__ nf, float* __restrict__ agg)
{
  __shared__ float ew1l[128][8];    // 4 KB {w0..w5, b, pad}
  __shared__ int tgtl[128];         // 512 B
  __shared__ short hm[128][136];    // 34816 B   -> total 39424 B => 4 blocks/CU

  const int t = threadIdx.x;
  const int e0 = blockIdx.x*128;
  const int w = t >> 6, lane = t & 63, l15 = lane & 15, q = lane >> 4;
  const int base = e0 + w*32;

  // ---- early global gathers (before the single barrier) ----
  int i0 = base + l15;      if (i0 >= E_EDGES) i0 = E_EDGES - 1;
  int i1 = base + 16 + l15; if (i1 >= E_EDGES) i1 = E_EDGES - 1;
  int s0 = srcs_s[i0], s1 = srcs_s[i1];
  int g0 = tgts_s[i0], g1 = tgts_s[i1];

  bf8 an0[4], an1[4];
  {
    const short* n0p = nf + (size_t)s0*HD + q*8;
    const short* n1p = nf + (size_t)s1*HD + q*8;
    #pragma unroll
    for (int kt=0;kt<4;kt++){ an0[kt] = *(const bf8*)(n0p + kt*32); an1[kt] = *(const bf8*)(n1p + kt*32); }
  }
  // per-lane pos (dies after stage 1)
  float a0=npos[s0*3+0], a1=npos[s0*3+1], a2=npos[s0*3+2];
  float a3=gpos[g0*3+0], a4=gpos[g0*3+1], a5=gpos[g0*3+2];
  float b0=npos[s1*3+0], b1=npos[s1*3+1], b2=npos[s1*3+2];
  float b3=gpos[g1*3+0], b4=gpos[g1*3+1], b5=gpos[g1*3+2];

  if (t < 128){
    int idx = e0 + t; if (idx >= E_EDGES) idx = E_EDGES - 1;
    tgtl[t] = tgts_s[idx];
    *(f32x4*)&ew1l[t][0] = *(const f32x4*)&ew1c_g[t*8];
    *(f32x4*)&ew1l[t][4] = *(const f32x4*)&ew1c_g[t*8 + 4];
  }
  __syncthreads();   // the ONLY block-wide barrier

  // ---- stage 1: h = silu(pos6@ew1+eb1) -> hm, wave-local rows ----
  {
    int r0 = w*32 + l15, r1 = r0 + 16;
    #pragma unroll
    for (int pg=0; pg<4; pg++){
      bf8 pk0, pk1;
      #pragma unroll
      for (int j=0;j<8;j++){
        int n = q*32 + pg*8 + j;
        f32x4 wa = *(const f32x4*)&ew1l[n][0];
        f32x4 wb = *(const f32x4*)&ew1l[n][4];
        float v0 = wb[2] + a0*wa[0] + a1*wa[1] + a2*wa[2] + a3*wa[3] + a4*wb[0] + a5*wb[1];
        v0 = v0 / (1.f + __expf(-v0));
        pk0[j] = f2bf(v0);
        float v1 = wb[2] + b0*wa[0] + b1*wa[1] + b2*wa[2] + b3*wa[3] + b4*wb[0] + b5*wb[1];
        v1 = v1 / (1.f + __expf(-v1));
        pk1[j] = f2bf(v1);
      }
      *(bf8*)&hm[r0][q*32 + pg*8] = pk0;
      *(bf8*)&hm[r1][q*32 + pg*8] = pk1;
    }
  }

  // ---- stage 2: msg_hidden = silu(an@mw1a + ah@W_combo + b_combo) -> hm (overwrite) ----
  bf8 ah0[4], ah1[4];
  #pragma unroll
  for (int kt=0;kt<4;kt++){
    ah0[kt] = *(const bf8*)&hm[w*32 + l15][kt*32 + q*8];
    ah1[kt] = *(const bf8*)&hm[w*32 + 16 + l15][kt*32 + q*8];
  }
  #pragma unroll
  for (int ct=0; ct<8; ct++){
    bf8 bw1[4], bwc[4];
    #pragma unroll
    for (int kt=0;kt<4;kt++){
      bw1[kt] = *(const bf8*)(mw1t + (ct*16 + l15)*256 + kt*32 + q*8);
      bwc[kt] = *(const bf8*)(wcombot + (ct*16 + l15)*HD + kt*32 + q*8);
    }
    f32x4 acc0 = {0.f,0.f,0.f,0.f}, acc1 = {0.f,0.f,0.f,0.f};
    #pragma unroll
    for (int kt=0;kt<4;kt++){
      acc0 = __builtin_amdgcn_mfma_f32_16x16x32_bf16(an0[kt], bw1[kt], acc0, 0,0,0);
      acc1 = __builtin_amdgcn_mfma_f32_16x16x32_bf16(an1[kt], bw1[kt], acc1, 0,0,0);
    }
    #pragma unroll
    for (int kt=0;kt<4;kt++){
      acc0 = __builtin_amdgcn_mfma_f32_16x16x32_bf16(ah0[kt], bwc[kt], acc0, 0,0,0);
      acc1 = __builtin_amdgcn_mfma_f32_16x16x32_bf16(ah1[kt], bwc[kt], acc1, 0,0,0);
    }
    float bias = bcombo[ct*16 + l15];
    int col = ct*16 + l15;
    #pragma unroll
    for (int r=0;r<4;r++){
      float v0 = acc0[r] + bias;
      v0 = v0 / (1.f + __expf(-v0));
      hm[w*32 + q*4 + r][col] = f2bf(v0);
      float v1 = acc1[r] + bias;
      v1 = v1 / (1.f + __expf(-v1));
      hm[w*32 + 16 + q*4 + r][col] = f2bf(v1);
    }
  }

  bf8 am0[4], am1[4];
  #pragma unroll
  for (int kt=0;kt<4;kt++){
    am0[kt] = *(const bf8*)&hm[w*32 + l15][kt*32 + q*8];
    am1[kt] = *(const bf8*)&hm[w*32 + 16 + l15][kt*32 + q*8];
  }

  float* msgf_w = (float*)&hm[w*32][0];   // per-wave fp32 arena [16][132]
  int lim0 = E_EDGES - base;      if (lim0 > 16) lim0 = 16;
  int lim1 = E_EDGES - base - 16; if (lim1 > 16) lim1 = 16;
  int c2 = lane*2;
  int cur = -1; float sx = 0.f, sy = 0.f;

  #pragma unroll
  for (int ct=0; ct<8; ct++){
    f32x4 acc = {0.f,0.f,0.f,0.f};
    #pragma unroll
    for (int kt=0;kt<4;kt++){
      bf8 b = *(const bf8*)(mw2t + (ct*16 + l15)*HD + kt*32 + q*8);
      acc = __builtin_amdgcn_mfma_f32_16x16x32_bf16(am0[kt], b, acc, 0,0,0);
    }
    float bias = mb2[ct*16 + l15];
    int col = ct*16 + l15;
    #pragma unroll
    for (int r=0;r<4;r++) msgf_w[(q*4 + r)*132 + col] = acc[r] + bias;
  }
  if (lim0 > 0){
    cur = tgtl[w*32];
    for (int r=0; r<lim0; r++){
      int tg = tgtl[w*32 + r];
      float2 v = *(const float2*)&msgf_w[r*132 + c2];
      if (tg != cur){
        atomicAdd(&agg[(size_t)cur*HD + c2], sx);
        atomicAdd(&agg[(size_t)cur*HD + c2 + 1], sy);
        cur = tg; sx = v.x; sy = v.y;
      } else { sx += v.x; sy += v.y; }
    }
  }

  if (lim1 > 0){
    #pragma unroll
    for (int ct=0; ct<8; ct++){
      f32x4 acc = {0.f,0.f,0.f,0.f};
      #pragma unroll
      for (int kt=0;kt<4;kt++){
        bf8 b = *(const bf8*)(mw2t + (ct*16 + l15)*HD + kt*32 + q*8);
        acc = __builtin_amdgcn_mfma_f32_16x16x32_bf16(am1[kt], b, acc, 0,0,0);
      }
      float bias = mb2[ct*16 + l15];
      int col = ct*16 + l15;
      #pragma unroll
      for (int r=0;r<4;r++) msgf_w[(q*4 + r)*132 + col] = acc[r] + bias;
    }
    for (int r=0; r<lim1; r++){
      int tg = tgtl[w*32 + 16 + r];
      float2 v = *(const float2*)&msgf_w[r*132 + c2];
      if (tg != cur){
        atomicAdd(&agg[(size_t)cur*HD + c2], sx);
        atomicAdd(&agg[(size_t)cur*HD + c2 + 1], sy);
        cur = tg; sx = v.x; sy = v.y;
      } else { sx += v.x; sy += v.y; }
    }
  }
  if (cur >= 0){
    atomicAdd(&agg[(size_t)cur*HD + c2], sx);
    atomicAdd(&agg[(size_t)cur*HD + c2 + 1], sy);
  }
}

// ---------- update MLP (MFMA bf16, wave-local, no barrier), in-place over agg(=d_out) ----------
__global__ void update_mlp2_k(const float* __restrict__ agg, const int* __restrict__ offs,
                              const short* __restrict__ w1t, const float* __restrict__ b1,
                              const short* __restrict__ w2t, const float* __restrict__ b2,
                              float* __restrict__ out)
{
  __shared__ short hid[64][136];
  const int t = threadIdx.x;
  const int wave = t >> 6, lane = t & 63, l15 = lane & 15, q = lane >> 4;
  const int rw = blockIdx.x*64 + wave*16;

  int row = rw + l15;
  float c = (float)(offs[row+1] - offs[row]);
  float rcp = 1.0f / fmaxf(c, 1.0f);
  bf8 a[4];
  const float* ar = agg + (size_t)row*HD;
  #pragma unroll
  for (int kt=0; kt<4; kt++) a[kt] = load_pack8(ar + kt*32 + q*8, rcp);

  #pragma unroll
  for (int ct=0; ct<8; ct++){
    f32x4 acc = {0.f,0.f,0.f,0.f};
    #pragma unroll
    for (int kt=0; kt<4; kt++){
      bf8 b = *(const bf8*)(w1t + (ct*16 + l15)*HD + kt*32 + q*8);
      acc = __builtin_amdgcn_mfma_f32_16x16x32_bf16(a[kt], b, acc, 0, 0, 0);
    }
    float bias = b1[ct*16 + l15];
    #pragma unroll
    for (int r=0;r<4;r++){
      float v = acc[r] + bias;
      v = v / (1.f + __expf(-v));
      hid[wave*16 + q*4 + r][ct*16 + l15] = f2bf(v);
    }
  }
  bf8 a2[4];
  #pragma unroll
  for (int kt=0;kt<4;kt++) a2[kt] = *(const bf8*)&hid[wave*16 + l15][kt*32 + q*8];
  #pragma unroll
  for (int ct=0; ct<8; ct++){
    f32x4 acc = {0.f,0.f,0.f,0.f};
    #pragma unroll
    for (int kt=0;kt<4;kt++){
      bf8 b = *(const bf8*)(w2t + (ct*16 + l15)*HD + kt*32 + q*8);
      acc = __builtin_amdgcn_mfma_f32_16x16x32_bf16(a2[kt], b, acc, 0, 0, 0);
    }
    float bias = b2[ct*16 + l15];
    #pragma unroll
    for (int r=0;r<4;r++)
      out[(size_t)(rw + q*4 + r)*HD + ct*16 + l15] = acc[r] + bias;
  }
}

extern "C" void kernel_launch(void* const* d_in, const int* in_sizes, int n_in,
                              void* d_out, int out_size, void* d_ws, size_t ws_size,
                              hipStream_t stream)
{
  const float* node_features = (const float*)d_in[0];
  const float* node_pos      = (const float*)d_in[1];
  const float* grid_pos      = (const float*)d_in[2];
  const int*   edge_index    = (const int*)d_in[3];
  const float* nm_w1 = (const float*)d_in[4];
  const float* nm_b1 = (const float*)d_in[5];
  const float* nm_w2 = (const float*)d_in[6];
  const float* nm_b2 = (const float*)d_in[7];
  const float* em_w1 = (const float*)d_in[8];
  const float* em_b1 = (const float*)d_in[9];
  const float* em_w2 = (const float*)d_in[10];
  const float* em_b2 = (const float*)d_in[11];
  const float* mm_w1 = (const float*)d_in[12];
  const float* mm_b1 = (const float*)d_in[13];
  const float* mm_w2 = (const float*)d_in[14];
  const float* mm_b2 = (const float*)d_in[15];
  const float* um_w1 = (const float*)d_in[16];
  const float* um_b1 = (const float*)d_in[17];
  const float* um_w2 = (const float*)d_in[18];
  const float* um_b2 = (const float*)d_in[19];
  float* out = (float*)d_out;

  char* ws = (char*)d_ws;
  short* nf     = (short*)ws;                        // 16 MB  bf16 (only first 32768 rows used)
  int*   counts = (int*)  (ws + 16777216ull);        // 128 KB
  int*   offs   = (int*)  (ws + 16908288ull);        // 128 KB + 64
  short* wts    = (short*)(ws + 17039424ull);        // 256 KB bf16 transposed
  short* wcombot= (short*)(ws + 17301568ull);        // 32 KB
  float* bcombo = (float*)(ws + 17334336ull);        // 512 B
  float* ew1c   = (float*)(ws + 17334848ull);        // 4 KB
  int*   srcs_s = (int*)  (ws + 17338944ull);        // 2.4 MB
  int*   tgts_s = (int*)  (ws + 19738944ull);        // 2.4 MB

  short* nmw1t = wts;
  short* nmw2t = wts + 16384;
  short* mmw1t = wts + 49152;   // [n][256]
  short* mmw2t = wts + 81920;
  short* umw1t = wts + 98304;
  short* umw2t = wts + 114688;

  float* agg = out;  // accumulate mean-numerator directly in d_out

  (void)hipMemsetAsync(counts, 0, 131072, stream);
  (void)hipMemsetAsync(out, 0, (size_t)G_GRID*HD*4, stream);

  prep_w_k<<<512, 256, 0, stream>>>(nm_w1, nm_w2, em_w2, mm_w1, mm_w2, um_w1, um_w2, wts);
  prep_combo_k<<<65, 256, 0, stream>>>(em_w1, em_b1, em_w2, em_b2, mm_w1, mm_b1,
                                       wcombot, bcombo, ew1c);
  // src indices are drawn from [0, G_GRID): only first 32768 nf rows are ever read
  node_mlp_k<<<G_GRID/64, 256, 0, stream>>>(node_features, nmw1t, nm_b1, nmw2t, nm_b2, nf);
  count_k<<<(E_EDGES+255)/256, 256, 0, stream>>>(edge_index, counts);
  scan_k<<<1, 1024, 0, stream>>>(counts, offs);
  scatter_k<<<(E_EDGES+255)/256, 256, 0, stream>>>(edge_index, offs, counts, srcs_s, tgts_s);
  edge_msg5_k<<<(E_EDGES + 127)/128, 256, 0, stream>>>(srcs_s, tgts_s, node_pos, grid_pos,
      ew1c, bcombo, mmw1t, wcombot, mmw2t, mm_b2, nf, agg);
  update_mlp2_k<<<G_GRID/64, 256, 0, stream>>>(agg, offs, umw1t, um_b1, umw2t, um_b2, out);
}